// Round 1
// baseline (192.163 us; speedup 1.0000x reference)
//
#include <hip/hip_runtime.h>
#include <hip/hip_bf16.h>
#include <math.h>

#define NF 512
#define ND 16
#define ROWS 16

__global__ __launch_bounds__(256) void deepfm_fused(
    const float* __restrict__ x,
    const float* __restrict__ fm_w, const float* __restrict__ fm_b,
    const float* __restrict__ lin_w, const float* __restrict__ lin_b,
    const float* __restrict__ w1, const float* __restrict__ b1,
    const float* __restrict__ w2, const float* __restrict__ b2,
    const float* __restrict__ w3, const float* __restrict__ b3,
    const float* __restrict__ wo, const float* __restrict__ bo,
    const float* __restrict__ bias,
    float* __restrict__ out, int B)
{
    // padded strides (all %32==4 -> distinct banks per row-group, 16B aligned)
    __shared__ float x_lds[ROWS][516];
    __shared__ float h1_lds[ROWS][132];
    __shared__ float h2_lds[ROWS][68];
    __shared__ float h3_lds[ROWS][36];
    __shared__ float s1_lds[ROWS];

    const int t = threadIdx.x;
    const int row0 = blockIdx.x * ROWS;

    // ---- phase 0: stage x tile (16 rows x 512 f32), fully coalesced float4
    #pragma unroll
    for (int k = 0; k < 8; ++k) {
        int idx = t + 256 * k;      // float4 index within tile
        int r = idx >> 7;           // 128 float4 per row
        int c = idx & 127;
        int row = row0 + r;
        float4 v = make_float4(0.f, 0.f, 0.f, 0.f);
        if (row < B) v = ((const float4*)(x + (size_t)row * NF))[c];
        *(float4*)&x_lds[r][c * 4] = v;
    }
    __syncthreads();

    const int r   = t >> 4;   // row within tile
    const int c16 = t & 15;   // sub-lane role (d / col-group)

    // ---- FM second order + linear: thread (r, d=c16)
    {
        float sum_e = 0.f, sum_sq = 0.f;
        const float* wp = fm_w + c16;
        const float* bp = fm_b + c16;
        for (int f = 0; f < NF; f += 4) {
            float4 xv = *(const float4*)&x_lds[r][f];
            float xa[4] = {xv.x, xv.y, xv.z, xv.w};
            #pragma unroll
            for (int i = 0; i < 4; ++i) {
                float e = fmaf(xa[i], wp[(f + i) * ND], bp[(f + i) * ND]);
                sum_e += e;
                sum_sq = fmaf(e, e, sum_sq);
            }
        }
        float val = fmaf(sum_e, sum_e, -sum_sq);  // sum_emb^2 - square_sum

        // linear part: lane c16 covers f = c16*32 .. +31
        float lin = 0.f;
        const int f0 = c16 * 32;
        #pragma unroll
        for (int f = 0; f < 32; f += 4) {
            float4 xv = *(const float4*)&x_lds[r][f0 + f];
            float4 wv = *(const float4*)&lin_w[f0 + f];
            lin = fmaf(xv.x, wv.x, lin);
            lin = fmaf(xv.y, wv.y, lin);
            lin = fmaf(xv.z, wv.z, lin);
            lin = fmaf(xv.w, wv.w, lin);
        }
        float red = fmaf(0.5f, val, lin);  // 0.5*val summed over d + linear summed
        #pragma unroll
        for (int m = 1; m < 16; m <<= 1) red += __shfl_xor(red, m);
        if (c16 == 0) s1_lds[r] = red + lin_b[0] + bias[0];
    }

    // ---- h1 = relu(x @ w1 + b1): thread (r, jg=c16) does cols jg*8..jg*8+7
    {
        float acc[8];
        const int j0 = c16 * 8;
        #pragma unroll
        for (int i = 0; i < 8; ++i) acc[i] = b1[j0 + i];
        for (int f = 0; f < NF; f += 4) {
            float4 xv = *(const float4*)&x_lds[r][f];
            float xa[4] = {xv.x, xv.y, xv.z, xv.w};
            #pragma unroll
            for (int i = 0; i < 4; ++i) {
                const float* wrow = w1 + (size_t)(f + i) * 128 + j0;
                float4 wa = *(const float4*)wrow;
                float4 wb = *(const float4*)(wrow + 4);
                float xf = xa[i];
                acc[0] = fmaf(xf, wa.x, acc[0]);
                acc[1] = fmaf(xf, wa.y, acc[1]);
                acc[2] = fmaf(xf, wa.z, acc[2]);
                acc[3] = fmaf(xf, wa.w, acc[3]);
                acc[4] = fmaf(xf, wb.x, acc[4]);
                acc[5] = fmaf(xf, wb.y, acc[5]);
                acc[6] = fmaf(xf, wb.z, acc[6]);
                acc[7] = fmaf(xf, wb.w, acc[7]);
            }
        }
        #pragma unroll
        for (int i = 0; i < 8; ++i) h1_lds[r][j0 + i] = fmaxf(acc[i], 0.f);
    }
    __syncthreads();

    // ---- h2 = relu(h1 @ w2 + b2): thread (r, c16) does cols c16*4..+3
    {
        float acc[4];
        const int c0 = c16 * 4;
        #pragma unroll
        for (int i = 0; i < 4; ++i) acc[i] = b2[c0 + i];
        for (int k = 0; k < 128; k += 4) {
            float4 hv = *(const float4*)&h1_lds[r][k];
            float ha[4] = {hv.x, hv.y, hv.z, hv.w};
            #pragma unroll
            for (int i = 0; i < 4; ++i) {
                float4 wv = *(const float4*)&w2[(size_t)(k + i) * 64 + c0];
                float hf = ha[i];
                acc[0] = fmaf(hf, wv.x, acc[0]);
                acc[1] = fmaf(hf, wv.y, acc[1]);
                acc[2] = fmaf(hf, wv.z, acc[2]);
                acc[3] = fmaf(hf, wv.w, acc[3]);
            }
        }
        #pragma unroll
        for (int i = 0; i < 4; ++i) h2_lds[r][c0 + i] = fmaxf(acc[i], 0.f);
    }
    __syncthreads();

    // ---- h3 = relu(h2 @ w3 + b3): thread (r, c16) does cols c16*2, c16*2+1
    {
        const int c0 = c16 * 2;
        float a0 = b3[c0], a1 = b3[c0 + 1];
        for (int k = 0; k < 64; k += 4) {
            float4 hv = *(const float4*)&h2_lds[r][k];
            float ha[4] = {hv.x, hv.y, hv.z, hv.w};
            #pragma unroll
            for (int i = 0; i < 4; ++i) {
                float2 wv = *(const float2*)&w3[(size_t)(k + i) * 32 + c0];
                a0 = fmaf(ha[i], wv.x, a0);
                a1 = fmaf(ha[i], wv.y, a1);
            }
        }
        h3_lds[r][c0]     = fmaxf(a0, 0.f);
        h3_lds[r][c0 + 1] = fmaxf(a1, 0.f);
    }
    __syncthreads();

    // ---- output: deep_out + s1 -> sigmoid
    {
        const int c0 = c16 * 2;
        float p = h3_lds[r][c0] * wo[c0] + h3_lds[r][c0 + 1] * wo[c0 + 1];
        #pragma unroll
        for (int m = 1; m < 16; m <<= 1) p += __shfl_xor(p, m);
        if (c16 == 0) {
            int row = row0 + r;
            if (row < B) {
                float z = p + bo[0] + s1_lds[r];
                out[row] = 1.0f / (1.0f + expf(-z));
            }
        }
    }
}

extern "C" void kernel_launch(void* const* d_in, const int* in_sizes, int n_in,
                              void* d_out, int out_size, void* d_ws, size_t ws_size,
                              hipStream_t stream) {
    const float* x     = (const float*)d_in[0];
    const float* fm_w  = (const float*)d_in[1];
    const float* fm_b  = (const float*)d_in[2];
    const float* lin_w = (const float*)d_in[3];
    const float* lin_b = (const float*)d_in[4];
    const float* w1    = (const float*)d_in[5];
    const float* b1    = (const float*)d_in[6];
    const float* w2    = (const float*)d_in[7];
    const float* b2    = (const float*)d_in[8];
    const float* w3    = (const float*)d_in[9];
    const float* b3    = (const float*)d_in[10];
    const float* wo    = (const float*)d_in[11];
    const float* bo    = (const float*)d_in[12];
    const float* bias  = (const float*)d_in[13];
    float* out = (float*)d_out;

    int B = in_sizes[0] / NF;
    int grid = (B + ROWS - 1) / ROWS;
    deepfm_fused<<<grid, 256, 0, stream>>>(x, fm_w, fm_b, lin_w, lin_b,
                                           w1, b1, w2, b2, w3, b3,
                                           wo, bo, bias, out, B);
}

// Round 2
// 129.055 us; speedup vs baseline: 1.4890x; 1.4890x over previous
//
#include <hip/hip_runtime.h>
#include <hip/hip_bf16.h>
#include <math.h>

#define NF 512
#define ND 16
#define H1N 128
#define H2N 64
#define H3N 32
#define ROWS 32
#define THREADS 512

// MFMA 16x16x32 bf16 operand k-pattern:
// 1 = two 16x16x16-style halves: k = 4*(lane>>4) + (j&3) + 16*(j>>2)
// 0 = contiguous 8:              k = 8*(lane>>4) + j
#define K_INTERLEAVED 1

typedef __bf16 bf16x8 __attribute__((ext_vector_type(8)));
typedef float f32x4 __attribute__((ext_vector_type(4)));

static __device__ __forceinline__ unsigned short f2bf(float f) {
    __hip_bfloat16 h = __float2bfloat16(f);
    return *reinterpret_cast<unsigned short*>(&h);
}

// ---------------- prep: pre-swizzle w1 into MFMA B-fragment order (bf16),
// and pack (fm_w, fm_b) into interleaved float2 ----------------
__global__ __launch_bounds__(256) void deepfm_prep(
    const float* __restrict__ w1, const float* __restrict__ fm_w,
    const float* __restrict__ fm_b, void* __restrict__ ws)
{
    int tid = blockIdx.x * 256 + threadIdx.x;
    unsigned short* w1s = (unsigned short*)ws;                 // [16 ks][8 nt][64 lane][8] bf16
    float2* wb = (float2*)((char*)ws + 131072);                // [512*16] (w,b) pairs
    if (tid < 8192) {
        int ks = tid >> 9;
        int nt = (tid >> 6) & 7;
        int l  = tid & 63;
        int n  = nt * 16 + (l & 15);
        #pragma unroll
        for (int j = 0; j < 8; ++j) {
#if K_INTERLEAVED
            int k = 32 * ks + 4 * (l >> 4) + (j & 3) + 16 * (j >> 2);
#else
            int k = 32 * ks + 8 * (l >> 4) + j;
#endif
            w1s[tid * 8 + j] = f2bf(w1[k * H1N + n]);
        }
    } else {
        int i = tid - 8192;                                    // fm_w/fm_b are [512][16] row-major
        wb[i] = make_float2(fm_w[i], fm_b[i]);
    }
}

// ---------------- main fused kernel ----------------
__global__ __launch_bounds__(THREADS) void deepfm_main(
    const float* __restrict__ x,
    const float* __restrict__ lin_w, const float* __restrict__ lin_bp,
    const float* __restrict__ b1p,
    const float* __restrict__ w2, const float* __restrict__ b2p,
    const float* __restrict__ w3, const float* __restrict__ b3p,
    const float* __restrict__ wop, const float* __restrict__ bop,
    const float* __restrict__ biasp,
    const void* __restrict__ ws,
    float* __restrict__ out, int B)
{
    __shared__ float h1_lds[ROWS][H1N + 4];
    __shared__ float h2_lds[ROWS][H2N + 4];
    __shared__ float h3_lds[ROWS][H3N + 4];
    __shared__ float s1_lds[ROWS];

    const int t = threadIdx.x;
    const int row0 = blockIdx.x * ROWS;

    // ---- phase 1: h1 = relu(x @ w1 + b1) via bf16 MFMA (no LDS, no barriers) ----
    {
        const int wid = t >> 6, lane = t & 63;
        const int mh = wid >> 2;          // M-half: rows mh*16 .. +15
        const int nq = wid & 3;           // N-quarter: cols nq*32 .. +31
        int arow = row0 + mh * 16 + (lane & 15);
        if (arow >= B) arow = B - 1;
        const int kg = lane >> 4;         // 0..3
        const float* xr = x + (size_t)arow * NF;
        const unsigned short* wsu = (const unsigned short*)ws;

        f32x4 acc0 = {0.f, 0.f, 0.f, 0.f};
        f32x4 acc1 = {0.f, 0.f, 0.f, 0.f};

        #pragma unroll 4
        for (int ks = 0; ks < 16; ++ks) {
#if K_INTERLEAVED
            float4 alo = *(const float4*)(xr + 32 * ks + 4 * kg);
            float4 ahi = *(const float4*)(xr + 32 * ks + 4 * kg + 16);
#else
            float4 alo = *(const float4*)(xr + 32 * ks + 8 * kg);
            float4 ahi = *(const float4*)(xr + 32 * ks + 8 * kg + 4);
#endif
            union { unsigned short u[8]; bf16x8 v; } af;
            af.u[0] = f2bf(alo.x); af.u[1] = f2bf(alo.y);
            af.u[2] = f2bf(alo.z); af.u[3] = f2bf(alo.w);
            af.u[4] = f2bf(ahi.x); af.u[5] = f2bf(ahi.y);
            af.u[6] = f2bf(ahi.z); af.u[7] = f2bf(ahi.w);

            bf16x8 bf0 = *(const bf16x8*)(wsu + ((size_t)(ks * 8 + nq * 2    ) * 64 + lane) * 8);
            bf16x8 bf1 = *(const bf16x8*)(wsu + ((size_t)(ks * 8 + nq * 2 + 1) * 64 + lane) * 8);

            acc0 = __builtin_amdgcn_mfma_f32_16x16x32_bf16(af.v, bf0, acc0, 0, 0, 0);
            acc1 = __builtin_amdgcn_mfma_f32_16x16x32_bf16(af.v, bf1, acc1, 0, 0, 0);
        }

        // epilogue: C/D layout col=lane&15, row=(lane>>4)*4+reg (m89-verified)
        const int drow = mh * 16 + (lane >> 4) * 4;
        const int c0 = nq * 32 + (lane & 15);
        const float bb0 = b1p[c0], bb1 = b1p[c0 + 16];
        #pragma unroll
        for (int i = 0; i < 4; ++i) {
            h1_lds[drow + i][c0]      = fmaxf(acc0[i] + bb0, 0.f);
            h1_lds[drow + i][c0 + 16] = fmaxf(acc1[i] + bb1, 0.f);
        }
    }

    // ---- phase 2: FM second-order + linear (fp32), writes s1_lds[r] ----
    {
        const int r = t >> 4, d = t & 15;
        int row = row0 + r;
        if (row >= B) row = B - 1;
        const float* xr = x + (size_t)row * NF;
        const float2* wb = (const float2*)((const char*)ws + 131072);

        float se = 0.f, sq = 0.f;
        for (int f = 0; f < NF; f += 4) {
            float4 xv = *(const float4*)(xr + f);
            float xa[4] = {xv.x, xv.y, xv.z, xv.w};
            #pragma unroll
            for (int i = 0; i < 4; ++i) {
                float2 p = wb[(f + i) * ND + d];
                float e = fmaf(xa[i], p.x, p.y);
                se += e;
                sq = fmaf(e, e, sq);
            }
        }
        float val = fmaf(se, se, -sq);   // sum_e^2 - square_sum (per d)

        // linear part: lane d covers f = d*32 .. +31
        float lin = 0.f;
        const int f0 = d * 32;
        #pragma unroll
        for (int f = 0; f < 32; f += 4) {
            float4 xv = *(const float4*)(xr + f0 + f);
            float4 wv = *(const float4*)(lin_w + f0 + f);
            lin = fmaf(xv.x, wv.x, lin);
            lin = fmaf(xv.y, wv.y, lin);
            lin = fmaf(xv.z, wv.z, lin);
            lin = fmaf(xv.w, wv.w, lin);
        }
        float red = fmaf(0.5f, val, lin);
        #pragma unroll
        for (int m = 1; m < 16; m <<= 1) red += __shfl_xor(red, m);
        if (d == 0) s1_lds[r] = red + lin_bp[0] + biasp[0];
    }
    __syncthreads();

    // ---- phase 3: h2 = relu(h1 @ w2 + b2), thread (r, c16) -> 4 cols ----
    {
        const int r = t >> 4, c16 = t & 15;
        const int c0 = c16 * 4;
        float acc[4];
        #pragma unroll
        for (int i = 0; i < 4; ++i) acc[i] = b2p[c0 + i];
        for (int k = 0; k < H1N; k += 4) {
            float4 hv = *(const float4*)&h1_lds[r][k];
            float ha[4] = {hv.x, hv.y, hv.z, hv.w};
            #pragma unroll
            for (int i = 0; i < 4; ++i) {
                float4 wv = *(const float4*)&w2[(size_t)(k + i) * H2N + c0];
                acc[0] = fmaf(ha[i], wv.x, acc[0]);
                acc[1] = fmaf(ha[i], wv.y, acc[1]);
                acc[2] = fmaf(ha[i], wv.z, acc[2]);
                acc[3] = fmaf(ha[i], wv.w, acc[3]);
            }
        }
        #pragma unroll
        for (int i = 0; i < 4; ++i) h2_lds[r][c0 + i] = fmaxf(acc[i], 0.f);
    }
    __syncthreads();

    // ---- phase 4: h3 = relu(h2 @ w3 + b3), thread (r, c16) -> 2 cols ----
    {
        const int r = t >> 4, c16 = t & 15;
        const int c0 = c16 * 2;
        float a0 = b3p[c0], a1 = b3p[c0 + 1];
        for (int k = 0; k < H2N; k += 4) {
            float4 hv = *(const float4*)&h2_lds[r][k];
            float ha[4] = {hv.x, hv.y, hv.z, hv.w};
            #pragma unroll
            for (int i = 0; i < 4; ++i) {
                float2 wv = *(const float2*)&w3[(size_t)(k + i) * H3N + c0];
                a0 = fmaf(ha[i], wv.x, a0);
                a1 = fmaf(ha[i], wv.y, a1);
            }
        }
        h3_lds[r][c0]     = fmaxf(a0, 0.f);
        h3_lds[r][c0 + 1] = fmaxf(a1, 0.f);
    }
    __syncthreads();

    // ---- phase 5: output ----
    {
        const int r = t >> 4, c16 = t & 15;
        const int c0 = c16 * 2;
        float p = h3_lds[r][c0] * wop[c0] + h3_lds[r][c0 + 1] * wop[c0 + 1];
        #pragma unroll
        for (int m = 1; m < 16; m <<= 1) p += __shfl_xor(p, m);
        if (c16 == 0) {
            int row = row0 + r;
            if (row < B) {
                float z = p + bop[0] + s1_lds[r];
                out[row] = 1.0f / (1.0f + expf(-z));
            }
        }
    }
}

extern "C" void kernel_launch(void* const* d_in, const int* in_sizes, int n_in,
                              void* d_out, int out_size, void* d_ws, size_t ws_size,
                              hipStream_t stream) {
    const float* x     = (const float*)d_in[0];
    const float* fm_w  = (const float*)d_in[1];
    const float* fm_b  = (const float*)d_in[2];
    const float* lin_w = (const float*)d_in[3];
    const float* lin_b = (const float*)d_in[4];
    const float* w1    = (const float*)d_in[5];
    const float* b1    = (const float*)d_in[6];
    const float* w2    = (const float*)d_in[7];
    const float* b2    = (const float*)d_in[8];
    const float* w3    = (const float*)d_in[9];
    const float* b3    = (const float*)d_in[10];
    const float* wo    = (const float*)d_in[11];
    const float* bo    = (const float*)d_in[12];
    const float* bias  = (const float*)d_in[13];
    float* out = (float*)d_out;

    int B = in_sizes[0] / NF;

    deepfm_prep<<<64, 256, 0, stream>>>(w1, fm_w, fm_b, d_ws);

    int grid = (B + ROWS - 1) / ROWS;
    deepfm_main<<<grid, THREADS, 0, stream>>>(x, lin_w, lin_b, b1, w2, b2,
                                              w3, b3, wo, bo, bias,
                                              d_ws, out, B);
}

// Round 14
// 27.813 us; speedup vs baseline: 6.9092x; 4.6402x over previous
//
#include <hip/hip_runtime.h>
#include <hip/hip_bf16.h>
#include <math.h>

#define NF 512
#define ND 16
#define H1N 128
#define H2N 64
#define H3N 32
#define ROWS 16
#define XPAD 520   // 512 + 8 bf16 pad

// ws byte offsets. Frag passes are contiguous 16KB slabs:
// p0-7: w1 tiles; p8: wh; p9: wl; p10: wsq; p11: 2*w*b; p12: [lin_w,0..0]
#define WS_W2F  212992   // 13*16384
#define WS_W3F  229376
#define WS_SB   233472
#define WS_SBB  233536

typedef __bf16 bf16x8 __attribute__((ext_vector_type(8)));
typedef float f32x4 __attribute__((ext_vector_type(4)));

union Frag { unsigned short u[8]; bf16x8 v; uint4 q; };

static __device__ __forceinline__ unsigned short f2bf(float f) {
    __hip_bfloat16 h = __float2bfloat16(f);
    return *reinterpret_cast<unsigned short*>(&h);
}
static __device__ __forceinline__ float bf2f(unsigned short u) {
    unsigned int b = (unsigned int)u << 16;
    return __uint_as_float(b);
}

// ---------------- prep: build all MFMA B-fragments + FM constants ----------------
__global__ __launch_bounds__(256) void deepfm_prep(
    const float* __restrict__ w1, const float* __restrict__ fm_w,
    const float* __restrict__ fm_b, const float* __restrict__ lin_w,
    const float* __restrict__ w2, const float* __restrict__ w3,
    void* __restrict__ ws)
{
    __shared__ float psb[256], psbb[256];
    const int t = threadIdx.x, b = blockIdx.x;

    if (b == 57) {  // FM constants: Sb[d] = sum_f fm_b, Sbb[d] = sum_f fm_b^2
        int d = t & 15, g = t >> 4;
        float sb = 0.f, sbb = 0.f;
        for (int f = g * 32; f < g * 32 + 32; ++f) {
            float bv = fm_b[f * ND + d];
            sb += bv; sbb = fmaf(bv, bv, sbb);
        }
        psb[t] = sb; psbb[t] = sbb;
        __syncthreads();
        if (t < 16) {
            float a = 0.f, c = 0.f;
            for (int g2 = 0; g2 < 16; ++g2) { a += psb[g2 * 16 + t]; c += psbb[g2 * 16 + t]; }
            ((float*)((char*)ws + WS_SB))[t]  = a;
            ((float*)((char*)ws + WS_SBB))[t] = c;
        }
        return;
    }

    int tid = b * 256 + t;
    Frag fr;
    if (tid < 13312) {           // 13 passes x 16 ks x 64 lanes (K=512)
        int p = tid >> 10, rem = tid & 1023;
        int ks = rem >> 6, l = rem & 63, n = l & 15, kg = l >> 4;
        #pragma unroll
        for (int j = 0; j < 8; ++j) {
            int k = 32 * ks + 4 * kg + (j & 3) + 16 * (j >> 2);
            float v;
            if (p < 8)        v = w1[(size_t)k * H1N + p * 16 + n];
            else if (p == 8)  v = fm_w[k * ND + n];
            else if (p == 9)  { float w = fm_w[k * ND + n]; v = w - bf2f(f2bf(w)); }
            else if (p == 10) { float w = fm_w[k * ND + n]; v = w * w; }
            else if (p == 11) v = 2.0f * fm_w[k * ND + n] * fm_b[k * ND + n];
            else              v = (n == 0) ? lin_w[k] : 0.0f;
            fr.u[j] = f2bf(v);
        }
    } else if (tid < 14336) {    // w2 frags: 4 tiles x 4 ks (K=128, N=64)
        int loc = tid - 13312;
        int tile = loc >> 8, ks = (loc >> 6) & 3, l = loc & 63;
        int n = tile * 16 + (l & 15), kg = l >> 4;
        #pragma unroll
        for (int j = 0; j < 8; ++j) {
            int k = 32 * ks + 4 * kg + (j & 3) + 16 * (j >> 2);
            fr.u[j] = f2bf(w2[(size_t)k * H2N + n]);
        }
    } else {                     // w3 frags: 2 tiles x 2 ks (K=64, N=32)
        int loc = tid - 14336;
        int tile = loc >> 7, ks = (loc >> 6) & 1, l = loc & 63;
        int n = tile * 16 + (l & 15), kg = l >> 4;
        #pragma unroll
        for (int j = 0; j < 8; ++j) {
            int k = 32 * ks + 4 * kg + (j & 3) + 16 * (j >> 2);
            fr.u[j] = f2bf(w3[(size_t)k * H3N + n]);
        }
    }
    *((uint4*)((unsigned short*)ws + (size_t)tid * 8)) = fr.q;
}

// ---------------- main fused kernel ----------------
__global__ __launch_bounds__(256) void deepfm_main(
    const float* __restrict__ x,
    const float* __restrict__ lin_b, const float* __restrict__ b1,
    const float* __restrict__ b2, const float* __restrict__ b3,
    const float* __restrict__ wo, const float* __restrict__ bo,
    const float* __restrict__ bias,
    const void* __restrict__ ws,
    float* __restrict__ out, int B)
{
    __shared__ unsigned short xh_lds[ROWS][XPAD];
    __shared__ unsigned short xl_lds[ROWS][XPAD];
    __shared__ float h1_lds[ROWS][H1N + 4];
    __shared__ float h2_lds[ROWS][H2N + 4];
    __shared__ float h3_lds[ROWS][H3N + 4];
    __shared__ float s_p[ROWS], s_q[ROWS], s_lin[ROWS];

    const int t = threadIdx.x;
    const int row0 = blockIdx.x * ROWS;
    const unsigned short* wsu = (const unsigned short*)ws;

    // ---- stage x once, coalesced; split into (xh, xl) bf16 pair in LDS ----
    #pragma unroll
    for (int kk = 0; kk < 8; ++kk) {
        int idx = t + 256 * kk;
        int r = idx >> 7, c4 = idx & 127;
        float4 v = *(const float4*)(x + (size_t)(row0 + r) * NF + c4 * 4);
        float va[4] = {v.x, v.y, v.z, v.w};
        ushort4 hi, lo;
        unsigned short hu[4], lu[4];
        #pragma unroll
        for (int e = 0; e < 4; ++e) {
            hu[e] = f2bf(va[e]);
            lu[e] = f2bf(va[e] - bf2f(hu[e]));
        }
        hi.x = hu[0]; hi.y = hu[1]; hi.z = hu[2]; hi.w = hu[3];
        lo.x = lu[0]; lo.y = lu[1]; lo.z = lu[2]; lo.w = lu[3];
        *(ushort4*)&xh_lds[r][c4 * 4] = hi;
        *(ushort4*)&xl_lds[r][c4 * 4] = lo;
    }
    __syncthreads();

    const int wid = t >> 6, l = t & 63;
    const int lr = l & 15, kg = l >> 4;

    if (wid >= 2) {
        // ---- h1 GEMM: wave2 -> cols 0-63, wave3 -> cols 64-127 ----
        f32x4 acc[4] = {{0.f,0.f,0.f,0.f},{0.f,0.f,0.f,0.f},{0.f,0.f,0.f,0.f},{0.f,0.f,0.f,0.f}};
        const int tbase = (wid - 2) * 4;
        #pragma unroll
        for (int ks = 0; ks < 16; ++ks) {
            Frag fa;
            *(ushort4*)&fa.u[0] = *(const ushort4*)&xh_lds[lr][32 * ks + 4 * kg];
            *(ushort4*)&fa.u[4] = *(const ushort4*)&xh_lds[lr][32 * ks + 4 * kg + 16];
            #pragma unroll
            for (int p = 0; p < 4; ++p) {
                bf16x8 bv = *(const bf16x8*)(wsu + ((size_t)(tbase + p) * 1024 + ks * 64 + l) * 8);
                acc[p] = __builtin_amdgcn_mfma_f32_16x16x32_bf16(fa.v, bv, acc[p], 0, 0, 0);
            }
        }
        #pragma unroll
        for (int p = 0; p < 4; ++p) {
            int col = (tbase + p) * 16 + lr;
            float bb = b1[col];
            #pragma unroll
            for (int i = 0; i < 4; ++i)
                h1_lds[kg * 4 + i][col] = fmaxf(acc[p][i] + bb, 0.f);
        }
    } else if (wid == 0) {
        // ---- FM P-tile: P = xh@wh + xh@wl + xl@wh (split-bf16 high precision) ----
        f32x4 a1 = {0.f,0.f,0.f,0.f}, a2 = {0.f,0.f,0.f,0.f}, a3 = {0.f,0.f,0.f,0.f};
        #pragma unroll
        for (int ks = 0; ks < 16; ++ks) {
            Frag fh, fl;
            *(ushort4*)&fh.u[0] = *(const ushort4*)&xh_lds[lr][32 * ks + 4 * kg];
            *(ushort4*)&fh.u[4] = *(const ushort4*)&xh_lds[lr][32 * ks + 4 * kg + 16];
            *(ushort4*)&fl.u[0] = *(const ushort4*)&xl_lds[lr][32 * ks + 4 * kg];
            *(ushort4*)&fl.u[4] = *(const ushort4*)&xl_lds[lr][32 * ks + 4 * kg + 16];
            bf16x8 bwh = *(const bf16x8*)(wsu + ((size_t)8 * 1024 + ks * 64 + l) * 8);
            bf16x8 bwl = *(const bf16x8*)(wsu + ((size_t)9 * 1024 + ks * 64 + l) * 8);
            a1 = __builtin_amdgcn_mfma_f32_16x16x32_bf16(fh.v, bwh, a1, 0, 0, 0);
            a2 = __builtin_amdgcn_mfma_f32_16x16x32_bf16(fh.v, bwl, a2, 0, 0, 0);
            a3 = __builtin_amdgcn_mfma_f32_16x16x32_bf16(fl.v, bwh, a3, 0, 0, 0);
        }
        float sbd = ((const float*)((const char*)ws + WS_SB))[lr];
        float sq[4];
        #pragma unroll
        for (int i = 0; i < 4; ++i) {
            float tt = a1[i] + a2[i] + a3[i] + sbd;  // sum_emb[row][d]
            sq[i] = tt * tt;
        }
        #pragma unroll
        for (int m = 1; m < 16; m <<= 1) {
            #pragma unroll
            for (int i = 0; i < 4; ++i) sq[i] += __shfl_xor(sq[i], m);
        }
        if (lr == 0) {
            #pragma unroll
            for (int i = 0; i < 4; ++i) s_p[kg * 4 + i] = sq[i];
        }
    } else {
        // ---- wid==1: S = xsq@wsq + xh@(2wb); L = xh@[lin_w|0] ----
        f32x4 aq = {0.f,0.f,0.f,0.f}, ar = {0.f,0.f,0.f,0.f}, al = {0.f,0.f,0.f,0.f};
        #pragma unroll
        for (int ks = 0; ks < 16; ++ks) {
            Frag fh, fl, fs;
            *(ushort4*)&fh.u[0] = *(const ushort4*)&xh_lds[lr][32 * ks + 4 * kg];
            *(ushort4*)&fh.u[4] = *(const ushort4*)&xh_lds[lr][32 * ks + 4 * kg + 16];
            *(ushort4*)&fl.u[0] = *(const ushort4*)&xl_lds[lr][32 * ks + 4 * kg];
            *(ushort4*)&fl.u[4] = *(const ushort4*)&xl_lds[lr][32 * ks + 4 * kg + 16];
            #pragma unroll
            for (int j = 0; j < 8; ++j) {
                float xf = bf2f(fh.u[j]) + bf2f(fl.u[j]);
                fs.u[j] = f2bf(xf * xf);
            }
            bf16x8 bsq = *(const bf16x8*)(wsu + ((size_t)10 * 1024 + ks * 64 + l) * 8);
            bf16x8 bb2 = *(const bf16x8*)(wsu + ((size_t)11 * 1024 + ks * 64 + l) * 8);
            bf16x8 bln = *(const bf16x8*)(wsu + ((size_t)12 * 1024 + ks * 64 + l) * 8);
            aq = __builtin_amdgcn_mfma_f32_16x16x32_bf16(fs.v, bsq, aq, 0, 0, 0);
            ar = __builtin_amdgcn_mfma_f32_16x16x32_bf16(fh.v, bb2, ar, 0, 0, 0);
            al = __builtin_amdgcn_mfma_f32_16x16x32_bf16(fh.v, bln, al, 0, 0, 0);
        }
        float sbbd = ((const float*)((const char*)ws + WS_SBB))[lr];
        float u[4];
        #pragma unroll
        for (int i = 0; i < 4; ++i) u[i] = aq[i] + ar[i] + sbbd;  // square_sum[row][d]
        #pragma unroll
        for (int m = 1; m < 16; m <<= 1) {
            #pragma unroll
            for (int i = 0; i < 4; ++i) u[i] += __shfl_xor(u[i], m);
        }
        if (lr == 0) {
            #pragma unroll
            for (int i = 0; i < 4; ++i) {
                s_q[kg * 4 + i]   = u[i];
                s_lin[kg * 4 + i] = al[i];   // lin col 0 lives in lanes lr==0
            }
        }
    }
    __syncthreads();

    // ---- h2 GEMM: each wave one 16-col tile (K=128) ----
    {
        f32x4 acc = {0.f,0.f,0.f,0.f};
        #pragma unroll
        for (int ks = 0; ks < 4; ++ks) {
            float4 vlo = *(const float4*)&h1_lds[lr][32 * ks + 4 * kg];
            float4 vhi = *(const float4*)&h1_lds[lr][32 * ks + 4 * kg + 16];
            Frag fa;
            fa.u[0] = f2bf(vlo.x); fa.u[1] = f2bf(vlo.y); fa.u[2] = f2bf(vlo.z); fa.u[3] = f2bf(vlo.w);
            fa.u[4] = f2bf(vhi.x); fa.u[5] = f2bf(vhi.y); fa.u[6] = f2bf(vhi.z); fa.u[7] = f2bf(vhi.w);
            bf16x8 bv = *(const bf16x8*)(wsu + WS_W2F / 2 + ((size_t)(wid * 4 + ks) * 64 + l) * 8);
            acc = __builtin_amdgcn_mfma_f32_16x16x32_bf16(fa.v, bv, acc, 0, 0, 0);
        }
        int col = wid * 16 + lr;
        float bb = b2[col];
        #pragma unroll
        for (int i = 0; i < 4; ++i) h2_lds[kg * 4 + i][col] = fmaxf(acc[i] + bb, 0.f);
    }
    __syncthreads();

    // ---- h3 GEMM: waves 0,1 (K=64, N=32) ----
    if (wid < 2) {
        f32x4 acc = {0.f,0.f,0.f,0.f};
        #pragma unroll
        for (int ks = 0; ks < 2; ++ks) {
            float4 vlo = *(const float4*)&h2_lds[lr][32 * ks + 4 * kg];
            float4 vhi = *(const float4*)&h2_lds[lr][32 * ks + 4 * kg + 16];
            Frag fa;
            fa.u[0] = f2bf(vlo.x); fa.u[1] = f2bf(vlo.y); fa.u[2] = f2bf(vlo.z); fa.u[3] = f2bf(vlo.w);
            fa.u[4] = f2bf(vhi.x); fa.u[5] = f2bf(vhi.y); fa.u[6] = f2bf(vhi.z); fa.u[7] = f2bf(vhi.w);
            bf16x8 bv = *(const bf16x8*)(wsu + WS_W3F / 2 + ((size_t)(wid * 2 + ks) * 64 + l) * 8);
            acc = __builtin_amdgcn_mfma_f32_16x16x32_bf16(fa.v, bv, acc, 0, 0, 0);
        }
        int col = wid * 16 + lr;
        float bb = b3[col];
        #pragma unroll
        for (int i = 0; i < 4; ++i) h3_lds[kg * 4 + i][col] = fmaxf(acc[i] + bb, 0.f);
    }
    __syncthreads();

    // ---- output ----
    {
        const int r = t >> 4, c = t & 15;
        float p = h3_lds[r][c * 2] * wo[c * 2] + h3_lds[r][c * 2 + 1] * wo[c * 2 + 1];
        #pragma unroll
        for (int m = 1; m < 16; m <<= 1) p += __shfl_xor(p, m);
        if (c == 0) {
            float z = p + bo[0] + s_lin[r] + lin_b[0] + bias[0]
                    + 0.5f * (s_p[r] - s_q[r]);
            out[row0 + r] = 1.0f / (1.0f + expf(-z));
        }
    }
}

extern "C" void kernel_launch(void* const* d_in, const int* in_sizes, int n_in,
                              void* d_out, int out_size, void* d_ws, size_t ws_size,
                              hipStream_t stream) {
    const float* x     = (const float*)d_in[0];
    const float* fm_w  = (const float*)d_in[1];
    const float* fm_b  = (const float*)d_in[2];
    const float* lin_w = (const float*)d_in[3];
    const float* lin_b = (const float*)d_in[4];
    const float* w1    = (const float*)d_in[5];
    const float* b1    = (const float*)d_in[6];
    const float* w2    = (const float*)d_in[7];
    const float* b2    = (const float*)d_in[8];
    const float* w3    = (const float*)d_in[9];
    const float* b3    = (const float*)d_in[10];
    const float* wo    = (const float*)d_in[11];
    const float* bo    = (const float*)d_in[12];
    const float* bias  = (const float*)d_in[13];
    float* out = (float*)d_out;

    int B = in_sizes[0] / NF;

    deepfm_prep<<<58, 256, 0, stream>>>(w1, fm_w, fm_b, lin_w, w2, w3, d_ws);

    int grid = B / ROWS;
    deepfm_main<<<grid, 256, 0, stream>>>(x, lin_b, b1, b2, b3, wo, bo, bias,
                                          d_ws, out, B);
}